// Round 14
// baseline (1212.333 us; speedup 1.0000x reference)
//
#include <hip/hip_runtime.h>
#include <math.h>

#define NN 100000
#define NE 1600000
#define NGR 1000
#define CHUNK 256    // edges per wave in k_agg; 6250 * 256 == NE exactly
#define NSLOT 64     // stats atomic spreading slots
#define SLOTF 128    // floats per slot (64 sum + 64 sumsq)
#define INSTF (NSLOT * SLOTF)   // floats per BN instance = 8192

// ---------------- CSR build ----------------
__global__ void k_count(const int* __restrict__ dst, int* __restrict__ deg) {
    int e = blockIdx.x * 256 + threadIdx.x;
    if (e < NE) atomicAdd(&deg[dst[e]], 1);
}

__global__ void k_blocksum(const int* __restrict__ deg, int* __restrict__ bsum) {
    __shared__ int sdata[4];
    int t = threadIdx.x;
    int base = blockIdx.x * 1024 + t * 4;
    int s = 0;
    #pragma unroll
    for (int k = 0; k < 4; k++) { int i = base + k; if (i < NN) s += deg[i]; }
    for (int o = 32; o; o >>= 1) s += __shfl_xor(s, o);
    if ((t & 63) == 0) sdata[t >> 6] = s;
    __syncthreads();
    if (t == 0) bsum[blockIdx.x] = sdata[0] + sdata[1] + sdata[2] + sdata[3];
}

__global__ void k_scanbsum(int* __restrict__ bsum, int nb, int* __restrict__ row_start) {
    if (threadIdx.x == 0 && blockIdx.x == 0) {
        int acc = 0;
        for (int i = 0; i < nb; i++) { int v = bsum[i]; bsum[i] = acc; acc += v; }
        row_start[NN] = acc;
    }
}

__global__ void k_scanblocks(const int* __restrict__ deg, const int* __restrict__ bsum,
                             int* __restrict__ row_start) {
    __shared__ int wsum[4];
    int t = threadIdx.x, lane = t & 63, w = t >> 6;
    int base = blockIdx.x * 1024 + t * 4;
    int a0 = (base     < NN) ? deg[base]     : 0;
    int a1 = (base + 1 < NN) ? deg[base + 1] : 0;
    int a2 = (base + 2 < NN) ? deg[base + 2] : 0;
    int a3 = (base + 3 < NN) ? deg[base + 3] : 0;
    int ts = a0 + a1 + a2 + a3;
    int incl = ts;
    for (int d = 1; d < 64; d <<= 1) { int v = __shfl_up(incl, d); if (lane >= d) incl += v; }
    if (lane == 63) wsum[w] = incl;
    __syncthreads();
    int woff = bsum[blockIdx.x];
    for (int i = 0; i < w; i++) woff += wsum[i];
    int excl = woff + incl - ts;
    if (base     < NN) row_start[base]     = excl;
    if (base + 1 < NN) row_start[base + 1] = excl + a0;
    if (base + 2 < NN) row_start[base + 2] = excl + a0 + a1;
    if (base + 3 < NN) row_start[base + 3] = excl + a0 + a1 + a2;
}

__global__ void k_fill(const int* __restrict__ src, const int* __restrict__ dst,
                       const int* __restrict__ row_start, int* __restrict__ cursor,
                       int* __restrict__ csr_src) {
    int e = blockIdx.x * 256 + threadIdx.x;
    if (e < NE) {
        int d = dst[e];
        int p = atomicAdd(&cursor[d], 1);
        csr_src[row_start[d] + p] = src[e];
    }
}

// ---------------- BN reduce: 64 slots -> compact (a, c) coeffs ----------------
__global__ void k_bnred(const float* __restrict__ slots, const float* __restrict__ g,
                        const float* __restrict__ be, float* __restrict__ ac) {
    int lane = threadIdx.x;   // 64 threads, 1 block
    float s1 = 0.f, s2 = 0.f;
    for (int s = 0; s < NSLOT; s++) {
        s1 += slots[s * SLOTF + lane];
        s2 += slots[s * SLOTF + 64 + lane];
    }
    float mu  = s1 * (1.0f / NN);
    float var = s2 * (1.0f / NN) - mu * mu;
    float inv = rsqrtf(var + 1e-5f);
    float a = g[lane] * inv;
    ac[lane] = a;
    ac[64 + lane] = be[lane] - mu * a;
}

// ---------------- edge-major aggregation: agg[dst] += norm(h[src]) ----------------
template <bool DONORM>
__global__ __launch_bounds__(64, 8) void k_agg(
    const float* __restrict__ hsrc, const float* __restrict__ ac,
    const int* __restrict__ row_start, const int* __restrict__ csr_src,
    float* __restrict__ agg)
{
    int lane = threadIdx.x;
    int c0 = blockIdx.x * CHUNK;
    float an = 1.f, cn = 0.f;
    if (DONORM) { an = ac[lane]; cn = ac[64 + lane]; }

    int lo = 0, hi = NN;
    while (lo < hi) { int mid = (lo + hi + 1) >> 1; if (row_start[mid] <= c0) lo = mid; else hi = mid - 1; }
    int r = lo;
    int rend = row_start[r + 1];
    float acc = 0.f;

    for (int g = 0; g < CHUNK; g += 8) {
        int e = c0 + g;
        float val[8];
        #pragma unroll
        for (int k = 0; k < 8; k++) val[k] = hsrc[csr_src[e + k] * 64 + lane];
        #pragma unroll
        for (int k = 0; k < 8; k++) {
            while (e + k >= rend) {             // wave-uniform
                atomicAdd(&agg[r * 64 + lane], acc);
                acc = 0.f; r++; rend = row_start[r + 1];
            }
            float v = val[k];
            if (DONORM) v = fmaxf(fmaf(an, v, cn), 0.f);
            acc += v;
        }
    }
    atomicAdd(&agg[r * 64 + lane], acc);
}

// block-level stats flush: LDS pre-reduce 4 waves, then 2 wave-atomics to a spread slot
__device__ inline void stats_flush(float* zbuf, int t, int lane, int w,
                                   float s1, float s2, float* stats_out) {
    __syncthreads();
    zbuf[w * 128 + lane] = s1;
    zbuf[w * 128 + 64 + lane] = s2;
    __syncthreads();
    if (t < 128) {
        float tot = zbuf[t] + zbuf[128 + t] + zbuf[256 + t] + zbuf[384 + t];
        atomicAdd(&stats_out[(blockIdx.x & (NSLOT - 1)) * SLOTF + t], tot);
    }
}

// ---------------- mlp1: z = (1+eps)*norm(h) + agg ; GEMM W1 + bias; BN1 stats ----------------
// launch_bounds(256,6): grid 1563 at 6 blocks/CU = 1536 co-resident -> 1.02 rounds (kills the
// 1.53-round tail seen at (256,4); VGPR cap at 6 waves/EU is 85, kernels are 44-64).
template <bool DONORM>
__global__ __launch_bounds__(256, 6) void k_mlp1(
    const float* __restrict__ hsrc, float* ubuf,
    const float* __restrict__ ac,
    const float* __restrict__ epsp, int layer,
    const float* __restrict__ W, const float* __restrict__ bb,
    float* __restrict__ stats_out)
{
    __shared__ float zbuf[64 * 64];
    int t = threadIdx.x, lane = t & 63, w = t >> 6;
    int rowbase = blockIdx.x * 64 + w * 16;
    float an = 1.f, cn = 0.f;
    if (DONORM) { an = ac[lane]; cn = ac[64 + lane]; }
    float epsl = 1.0f + epsp[layer];
    float* zw = &zbuf[w * 16 * 64];

    for (int r = 0; r < 16; r++) {
        int i = rowbase + r;
        float zf = 0.f;
        if (i < NN) {
            float hv = hsrc[i * 64 + lane];
            if (DONORM) hv = fmaxf(fmaf(an, hv, cn), 0.f);
            zf = fmaf(epsl, hv, ubuf[i * 64 + lane]);
        }
        zw[r * 64 + lane] = zf;
    }

    float4 wc4[16];
    #pragma unroll
    for (int k4 = 0; k4 < 16; k4++) {
        wc4[k4].x = W[(4 * k4 + 0) * 64 + lane];
        wc4[k4].y = W[(4 * k4 + 1) * 64 + lane];
        wc4[k4].z = W[(4 * k4 + 2) * 64 + lane];
        wc4[k4].w = W[(4 * k4 + 3) * 64 + lane];
    }
    float bj = bb[lane];
    float s1 = 0.f, s2 = 0.f;
    for (int r = 0; r < 16; r++) {
        int i = rowbase + r;
        if (i >= NN) break;
        float acc = bj;
        const float4* zr = (const float4*)&zw[r * 64];
        #pragma unroll
        for (int k4 = 0; k4 < 16; k4++) {
            float4 zv = zr[k4];
            acc = fmaf(zv.x, wc4[k4].x, acc);
            acc = fmaf(zv.y, wc4[k4].y, acc);
            acc = fmaf(zv.z, wc4[k4].z, acc);
            acc = fmaf(zv.w, wc4[k4].w, acc);
        }
        ubuf[i * 64 + lane] = acc;
        s1 += acc; s2 += acc * acc;
    }
    stats_flush(zbuf, t, lane, w, s1, s2, stats_out);
}

// ---------------- pass 2: BN1 apply + relu + GEMM2 + BN2 stats (+ optional u re-zero) ----------------
template <bool ZEROU>
__global__ __launch_bounds__(256, 6) void k_pass2(
    float* u,                     // read z-input; optionally zeroed for next layer's agg
    const float* __restrict__ ac1,
    const float* __restrict__ W, const float* __restrict__ bb,
    float* __restrict__ wout, float* __restrict__ stats_out)
{
    __shared__ float zbuf[64 * 64];
    int t = threadIdx.x, lane = t & 63, w = t >> 6;
    int rowbase = blockIdx.x * 64 + w * 16;
    float a = ac1[lane];
    float c = ac1[64 + lane];
    float* zw = &zbuf[w * 16 * 64];

    for (int r = 0; r < 16; r++) {
        int i = rowbase + r;
        float zf = 0.f;
        if (i < NN) {
            zf = fmaxf(fmaf(a, u[i * 64 + lane], c), 0.f);
            if (ZEROU) u[i * 64 + lane] = 0.f;
        }
        zw[r * 64 + lane] = zf;
    }

    float4 wc4[16];
    #pragma unroll
    for (int k4 = 0; k4 < 16; k4++) {
        wc4[k4].x = W[(4 * k4 + 0) * 64 + lane];
        wc4[k4].y = W[(4 * k4 + 1) * 64 + lane];
        wc4[k4].z = W[(4 * k4 + 2) * 64 + lane];
        wc4[k4].w = W[(4 * k4 + 3) * 64 + lane];
    }
    float bj = bb[lane];
    float s1 = 0.f, s2 = 0.f;
    for (int r = 0; r < 16; r++) {
        int i = rowbase + r;
        if (i >= NN) break;
        float acc = bj;
        const float4* zr = (const float4*)&zw[r * 64];
        #pragma unroll
        for (int k4 = 0; k4 < 16; k4++) {
            float4 zv = zr[k4];
            acc = fmaf(zv.x, wc4[k4].x, acc);
            acc = fmaf(zv.y, wc4[k4].y, acc);
            acc = fmaf(zv.z, wc4[k4].z, acc);
            acc = fmaf(zv.w, wc4[k4].w, acc);
        }
        wout[i * 64 + lane] = acc;
        s1 += acc; s2 += acc * acc;
    }
    stats_flush(zbuf, t, lane, w, s1, s2, stats_out);
}

// ---------------- final: BN2 apply ×3 + concat-GEMM (K=192) + bias + relu + gate ----------------
// Round-9 structure (proven): per-layer LDS staging, NO register prefetch pipeline
// (rounds 10/11: pf[16] live-range blowup -> scratch spill -> 9 GB HBM traffic).
__global__ __launch_bounds__(256, 6) void k_final(
    const float* __restrict__ w0, const float* __restrict__ w1, const float* __restrict__ w2,
    const float* __restrict__ acA, const float* __restrict__ acB, const float* __restrict__ acC,
    const float* __restrict__ lin1W, const float* __restrict__ lin1b,
    const float* __restrict__ gateW, const float* __restrict__ gateB,
    float* __restrict__ hh, float* __restrict__ gate)
{
    __shared__ float zbuf[64 * 64];
    int t = threadIdx.x, lane = t & 63, w = t >> 6;
    int rowbase = blockIdx.x * 64 + w * 16;
    float* zw = &zbuf[w * 16 * 64];

    float acc[16];
    #pragma unroll
    for (int r = 0; r < 16; r++) acc[r] = 0.f;

    for (int l = 0; l < 3; l++) {
        const float* wl = (l == 0) ? w0 : ((l == 1) ? w1 : w2);
        const float* ac = (l == 0) ? acA : ((l == 1) ? acB : acC);
        float a = ac[lane];
        float c = ac[64 + lane];

        for (int r = 0; r < 16; r++) {
            int i = rowbase + r;
            float zf = 0.f;
            if (i < NN) zf = fmaxf(fmaf(a, wl[i * 64 + lane], c), 0.f);
            zw[r * 64 + lane] = zf;
        }

        float4 wc4[16];
        #pragma unroll
        for (int k4 = 0; k4 < 16; k4++) {
            wc4[k4].x = lin1W[(l * 64 + 4 * k4 + 0) * 64 + lane];
            wc4[k4].y = lin1W[(l * 64 + 4 * k4 + 1) * 64 + lane];
            wc4[k4].z = lin1W[(l * 64 + 4 * k4 + 2) * 64 + lane];
            wc4[k4].w = lin1W[(l * 64 + 4 * k4 + 3) * 64 + lane];
        }

        #pragma unroll
        for (int r = 0; r < 16; r++) {
            const float4* zr = (const float4*)&zw[r * 64];
            float a2 = acc[r];
            #pragma unroll
            for (int k4 = 0; k4 < 16; k4++) {
                float4 zv = zr[k4];
                a2 = fmaf(zv.x, wc4[k4].x, a2);
                a2 = fmaf(zv.y, wc4[k4].y, a2);
                a2 = fmaf(zv.z, wc4[k4].z, a2);
                a2 = fmaf(zv.w, wc4[k4].w, a2);
            }
            acc[r] = a2;
        }
        __syncthreads();
    }

    float gw = gateW[lane];
    float gb = gateB[0];
    float lb = lin1b[lane];
    #pragma unroll
    for (int r = 0; r < 16; r++) {
        int i = rowbase + r;
        if (i < NN) {
            float h = fmaxf(acc[r] + lb, 0.f);
            hh[i * 64 + lane] = h;
            float gg = h * gw;
            for (int o = 32; o; o >>= 1) gg += __shfl_xor(gg, o);
            if (lane == 0) gate[i] = gg + gb;
        }
    }
}

// ---------------- graph boundaries + attentional pooling ----------------
__global__ void k_bounds(const int* __restrict__ batch_idx, int* __restrict__ gstart) {
    int g = blockIdx.x * 256 + threadIdx.x;
    if (g <= NGR) {
        int lo = 0, hi = NN;
        while (lo < hi) { int mid = (lo + hi) >> 1; if (batch_idx[mid] < g) lo = mid + 1; else hi = mid; }
        gstart[g] = lo;
    }
}

__global__ __launch_bounds__(256) void k_pool(const float* __restrict__ hh, const float* __restrict__ gate,
                                              const int* __restrict__ gstart, float* __restrict__ pooled) {
    __shared__ float red[4];
    __shared__ float pbuf[256];
    __shared__ float m_sh, d_sh;
    int g = blockIdx.x;
    int s = gstart[g], e = gstart[g + 1];
    int t = threadIdx.x, lane = t & 63, w = t >> 6;

    float m = -INFINITY;
    for (int i = s + t; i < e; i += 256) m = fmaxf(m, gate[i]);
    for (int o = 32; o; o >>= 1) m = fmaxf(m, __shfl_xor(m, o));
    if (lane == 0) red[w] = m;
    __syncthreads();
    if (t == 0) m_sh = fmaxf(fmaxf(red[0], red[1]), fmaxf(red[2], red[3]));
    __syncthreads();
    m = m_sh;

    float sum = 0.f;
    for (int i = s + t; i < e; i += 256) sum += expf(gate[i] - m);
    for (int o = 32; o; o >>= 1) sum += __shfl_xor(sum, o);
    if (lane == 0) red[w] = sum;
    __syncthreads();
    if (t == 0) d_sh = red[0] + red[1] + red[2] + red[3];
    __syncthreads();
    float denom = d_sh;

    float acc = 0.f;
    for (int i = s + w; i < e; i += 4) acc += expf(gate[i] - m) * hh[i * 64 + lane];
    pbuf[w * 64 + lane] = acc;
    __syncthreads();
    if (t < 64) {
        float tot = pbuf[t] + pbuf[64 + t] + pbuf[128 + t] + pbuf[192 + t];
        pooled[g * 64 + t] = (e > s) ? tot / denom : 0.f;
    }
}

// ---------------- launcher ----------------
extern "C" void kernel_launch(void* const* d_in, const int* in_sizes, int n_in,
                              void* d_out, int out_size, void* d_ws, size_t ws_size,
                              hipStream_t stream) {
    (void)in_sizes; (void)n_in; (void)out_size; (void)ws_size;
    const float* x     = (const float*)d_in[0];
    const int*   ei    = (const int*)d_in[1];
    const int*   src   = ei;
    const int*   dst   = ei + NE;
    const int*   bidx  = (const int*)d_in[2];
    const float* epsp  = (const float*)d_in[3];
    const float* W1    = (const float*)d_in[4];
    const float* b1    = (const float*)d_in[5];
    const float* g1    = (const float*)d_in[6];
    const float* be1   = (const float*)d_in[7];
    const float* W2    = (const float*)d_in[8];
    const float* b2    = (const float*)d_in[9];
    const float* g2    = (const float*)d_in[10];
    const float* be2   = (const float*)d_in[11];
    const float* lin1W = (const float*)d_in[12];
    const float* lin1b = (const float*)d_in[13];
    const float* gateW = (const float*)d_in[14];
    const float* gateB = (const float*)d_in[15];

    int* deg       = (int*)d_ws;
    int* cursor    = deg + NN;
    float* stats   = (float*)(cursor + NN);      // 6 instances * 8192 floats
    float* acbuf   = stats + 6 * INSTF;          // 6 * 128 floats compact BN coeffs
    int* row_start = (int*)(acbuf + 6 * 128);    // NN+1
    int* csr_src   = row_start + NN + 1;         // NE
    int* bsum      = csr_src + NE;               // 128
    float* u       = (float*)(bsum + 128);       // NN*64  (agg + gemm1 out, aliased)
    float* w0      = u   + (size_t)NN * 64;
    float* w1v     = w0  + (size_t)NN * 64;
    float* w2v     = w1v + (size_t)NN * 64;
    float* gate    = w2v + (size_t)NN * 64;      // NN
    int* gstart    = (int*)(gate + NN);          // NGR+1

    float* hh     = (float*)d_out;
    float* pooled = hh + (size_t)NN * 64;

    // zero deg, cursor, and all stats slots (ac buffers fully overwritten by k_bnred)
    hipMemsetAsync(d_ws, 0, (size_t)(2 * NN + 6 * INSTF) * 4, stream);

    k_count<<<(NE + 255) / 256, 256, 0, stream>>>(dst, deg);
    int nb = (NN + 1023) / 1024;
    k_blocksum<<<nb, 256, 0, stream>>>(deg, bsum);
    k_scanbsum<<<1, 64, 0, stream>>>(bsum, nb, row_start);
    k_scanblocks<<<nb, 256, 0, stream>>>(deg, bsum, row_start);
    k_fill<<<(NE + 255) / 256, 256, 0, stream>>>(src, dst, row_start, cursor, csr_src);

    int nagg  = NE / CHUNK;          // 6250 waves
    int nblk  = (NN + 63) / 64;      // 1563 blocks for GEMM kernels
    size_t hbytes = (size_t)NN * 64 * 4;

    float* sl0bn1 = stats + 0 * INSTF;  float* ac0bn1 = acbuf + 0 * 128;
    float* sl0bn2 = stats + 1 * INSTF;  float* ac0bn2 = acbuf + 1 * 128;
    float* sl1bn1 = stats + 2 * INSTF;  float* ac1bn1 = acbuf + 2 * 128;
    float* sl1bn2 = stats + 3 * INSTF;  float* ac1bn2 = acbuf + 3 * 128;
    float* sl2bn1 = stats + 4 * INSTF;  float* ac2bn1 = acbuf + 4 * 128;
    float* sl2bn2 = stats + 5 * INSTF;  float* ac2bn2 = acbuf + 5 * 128;

    // layer 0
    hipMemsetAsync(u, 0, hbytes, stream);
    k_agg<false><<<nagg, 64, 0, stream>>>(x, nullptr, row_start, csr_src, u);
    k_mlp1<false><<<nblk, 256, 0, stream>>>(x, u, nullptr, epsp, 0, W1, b1, sl0bn1);
    k_bnred<<<1, 64, 0, stream>>>(sl0bn1, g1, be1, ac0bn1);
    k_pass2<true><<<nblk, 256, 0, stream>>>(u, ac0bn1, W2, b2, w0, sl0bn2);
    k_bnred<<<1, 64, 0, stream>>>(sl0bn2, g2, be2, ac0bn2);
    // layer 1
    k_agg<true><<<nagg, 64, 0, stream>>>(w0, ac0bn2, row_start, csr_src, u);
    k_mlp1<true><<<nblk, 256, 0, stream>>>(w0, u, ac0bn2, epsp, 1, W1 + 4096, b1 + 64, sl1bn1);
    k_bnred<<<1, 64, 0, stream>>>(sl1bn1, g1 + 64, be1 + 64, ac1bn1);
    k_pass2<true><<<nblk, 256, 0, stream>>>(u, ac1bn1, W2 + 4096, b2 + 64, w1v, sl1bn2);
    k_bnred<<<1, 64, 0, stream>>>(sl1bn2, g2 + 64, be2 + 64, ac1bn2);
    // layer 2
    k_agg<true><<<nagg, 64, 0, stream>>>(w1v, ac1bn2, row_start, csr_src, u);
    k_mlp1<true><<<nblk, 256, 0, stream>>>(w1v, u, ac1bn2, epsp, 2, W1 + 8192, b1 + 128, sl2bn1);
    k_bnred<<<1, 64, 0, stream>>>(sl2bn1, g1 + 128, be1 + 128, ac2bn1);
    k_pass2<false><<<nblk, 256, 0, stream>>>(u, ac2bn1, W2 + 8192, b2 + 128, w2v, sl2bn2);
    k_bnred<<<1, 64, 0, stream>>>(sl2bn2, g2 + 128, be2 + 128, ac2bn2);

    k_final<<<nblk, 256, 0, stream>>>(w0, w1v, w2v, ac0bn2, ac1bn2, ac2bn2,
                                      lin1W, lin1b, gateW, gateB, hh, gate);
    k_bounds<<<(NGR + 256) / 256, 256, 0, stream>>>(bidx, gstart);
    k_pool<<<NGR, 256, 0, stream>>>(hh, gate, gstart, pooled);
}

// Round 15
// 789.033 us; speedup vs baseline: 1.5365x; 1.5365x over previous
//
#include <hip/hip_runtime.h>
#include <math.h>

#define NN 100000
#define NE 1600000
#define NGR 1000
#define CHUNK 256    // edges per wave in k_agg; 6250 * 256 == NE exactly
#define NSLOT 64     // stats atomic spreading slots
#define SLOTF 128    // floats per slot (64 sum + 64 sumsq)
#define INSTF (NSLOT * SLOTF)   // floats per BN instance = 8192

// bf16 helpers (RNE), no header dependency
__device__ inline unsigned short f2b(float f) {
    unsigned u = __float_as_uint(f);
    unsigned r = (u + 0x7FFF + ((u >> 16) & 1)) >> 16;
    return (unsigned short)r;
}
__device__ inline float b2f(unsigned short s) {
    return __uint_as_float(((unsigned)s) << 16);
}

// ---------------- CSR build ----------------
__global__ void k_count(const int* __restrict__ dst, int* __restrict__ deg) {
    int e = blockIdx.x * 256 + threadIdx.x;
    if (e < NE) atomicAdd(&deg[dst[e]], 1);
}

__global__ void k_blocksum(const int* __restrict__ deg, int* __restrict__ bsum) {
    __shared__ int sdata[4];
    int t = threadIdx.x;
    int base = blockIdx.x * 1024 + t * 4;
    int s = 0;
    #pragma unroll
    for (int k = 0; k < 4; k++) { int i = base + k; if (i < NN) s += deg[i]; }
    for (int o = 32; o; o >>= 1) s += __shfl_xor(s, o);
    if ((t & 63) == 0) sdata[t >> 6] = s;
    __syncthreads();
    if (t == 0) bsum[blockIdx.x] = sdata[0] + sdata[1] + sdata[2] + sdata[3];
}

__global__ void k_scanbsum(int* __restrict__ bsum, int nb, int* __restrict__ row_start) {
    if (threadIdx.x == 0 && blockIdx.x == 0) {
        int acc = 0;
        for (int i = 0; i < nb; i++) { int v = bsum[i]; bsum[i] = acc; acc += v; }
        row_start[NN] = acc;
    }
}

__global__ void k_scanblocks(const int* __restrict__ deg, const int* __restrict__ bsum,
                             int* __restrict__ row_start) {
    __shared__ int wsum[4];
    int t = threadIdx.x, lane = t & 63, w = t >> 6;
    int base = blockIdx.x * 1024 + t * 4;
    int a0 = (base     < NN) ? deg[base]     : 0;
    int a1 = (base + 1 < NN) ? deg[base + 1] : 0;
    int a2 = (base + 2 < NN) ? deg[base + 2] : 0;
    int a3 = (base + 3 < NN) ? deg[base + 3] : 0;
    int ts = a0 + a1 + a2 + a3;
    int incl = ts;
    for (int d = 1; d < 64; d <<= 1) { int v = __shfl_up(incl, d); if (lane >= d) incl += v; }
    if (lane == 63) wsum[w] = incl;
    __syncthreads();
    int woff = bsum[blockIdx.x];
    for (int i = 0; i < w; i++) woff += wsum[i];
    int excl = woff + incl - ts;
    if (base     < NN) row_start[base]     = excl;
    if (base + 1 < NN) row_start[base + 1] = excl + a0;
    if (base + 2 < NN) row_start[base + 2] = excl + a0 + a1;
    if (base + 3 < NN) row_start[base + 3] = excl + a0 + a1 + a2;
}

__global__ void k_fill(const int* __restrict__ src, const int* __restrict__ dst,
                       const int* __restrict__ row_start, int* __restrict__ cursor,
                       int* __restrict__ csr_src) {
    int e = blockIdx.x * 256 + threadIdx.x;
    if (e < NE) {
        int d = dst[e];
        int p = atomicAdd(&cursor[d], 1);
        csr_src[row_start[d] + p] = src[e];
    }
}

// ---------------- x -> bf16 table (layer-0 gather source) ----------------
__global__ void k_cvt(const float* __restrict__ in, ushort* __restrict__ out) {
    int i = (blockIdx.x * 256 + threadIdx.x) * 4;   // NN*64 = 6.4e6, %4==0; grid covers exactly
    float4 v = *(const float4*)&in[i];
    ushort4 o;
    o.x = f2b(v.x); o.y = f2b(v.y); o.z = f2b(v.z); o.w = f2b(v.w);
    *(ushort4*)&out[i] = o;
}

// ---------------- BN reduce: 64 slots -> compact (a, c) coeffs ----------------
__global__ void k_bnred(const float* __restrict__ slots, const float* __restrict__ g,
                        const float* __restrict__ be, float* __restrict__ ac) {
    int lane = threadIdx.x;   // 64 threads, 1 block
    float s1 = 0.f, s2 = 0.f;
    for (int s = 0; s < NSLOT; s++) {
        s1 += slots[s * SLOTF + lane];
        s2 += slots[s * SLOTF + 64 + lane];
    }
    float mu  = s1 * (1.0f / NN);
    float var = s2 * (1.0f / NN) - mu * mu;
    float inv = rsqrtf(var + 1e-5f);
    float a = g[lane] * inv;
    ac[lane] = a;
    ac[64 + lane] = be[lane] - mu * a;
}

// ---------------- edge-major aggregation: agg[dst] += norm(hb16[src]) ----------------
// Gather source is the bf16 h table (halves L3/HBM gather bytes; mlp1/final stay fp32).
template <bool DONORM>
__global__ __launch_bounds__(64, 8) void k_agg(
    const ushort* __restrict__ hb, const float* __restrict__ ac,
    const int* __restrict__ row_start, const int* __restrict__ csr_src,
    float* __restrict__ agg)
{
    int lane = threadIdx.x;
    int c0 = blockIdx.x * CHUNK;
    float an = 1.f, cn = 0.f;
    if (DONORM) { an = ac[lane]; cn = ac[64 + lane]; }

    int lo = 0, hi = NN;
    while (lo < hi) { int mid = (lo + hi + 1) >> 1; if (row_start[mid] <= c0) lo = mid; else hi = mid - 1; }
    int r = lo;
    int rend = row_start[r + 1];
    float acc = 0.f;

    for (int g = 0; g < CHUNK; g += 8) {
        int e = c0 + g;
        unsigned short val[8];
        #pragma unroll
        for (int k = 0; k < 8; k++) val[k] = hb[csr_src[e + k] * 64 + lane];
        #pragma unroll
        for (int k = 0; k < 8; k++) {
            while (e + k >= rend) {             // wave-uniform
                atomicAdd(&agg[r * 64 + lane], acc);
                acc = 0.f; r++; rend = row_start[r + 1];
            }
            float v = b2f(val[k]);
            if (DONORM) v = fmaxf(fmaf(an, v, cn), 0.f);
            acc += v;
        }
    }
    atomicAdd(&agg[r * 64 + lane], acc);
}

// block-level stats flush: LDS pre-reduce 4 waves, then 2 wave-atomics to a spread slot
__device__ inline void stats_flush(float* zbuf, int t, int lane, int w,
                                   float s1, float s2, float* stats_out) {
    __syncthreads();
    zbuf[w * 128 + lane] = s1;
    zbuf[w * 128 + 64 + lane] = s2;
    __syncthreads();
    if (t < 128) {
        float tot = zbuf[t] + zbuf[128 + t] + zbuf[256 + t] + zbuf[384 + t];
        atomicAdd(&stats_out[(blockIdx.x & (NSLOT - 1)) * SLOTF + t], tot);
    }
}

// ---------------- mlp1: z = (1+eps)*norm(h) + agg ; GEMM W1 + bias; BN1 stats ----------------
// (256,4) is the proven sweet spot; tightening launch bounds spills (rounds 10/11/14).
template <bool DONORM>
__global__ __launch_bounds__(256, 4) void k_mlp1(
    const float* __restrict__ hsrc, float* ubuf,
    const float* __restrict__ ac,
    const float* __restrict__ epsp, int layer,
    const float* __restrict__ W, const float* __restrict__ bb,
    float* __restrict__ stats_out)
{
    __shared__ float zbuf[64 * 64];
    int t = threadIdx.x, lane = t & 63, w = t >> 6;
    int rowbase = blockIdx.x * 64 + w * 16;
    float an = 1.f, cn = 0.f;
    if (DONORM) { an = ac[lane]; cn = ac[64 + lane]; }
    float epsl = 1.0f + epsp[layer];
    float* zw = &zbuf[w * 16 * 64];

    for (int r = 0; r < 16; r++) {
        int i = rowbase + r;
        float zf = 0.f;
        if (i < NN) {
            float hv = hsrc[i * 64 + lane];
            if (DONORM) hv = fmaxf(fmaf(an, hv, cn), 0.f);
            zf = fmaf(epsl, hv, ubuf[i * 64 + lane]);
        }
        zw[r * 64 + lane] = zf;
    }

    float4 wc4[16];
    #pragma unroll
    for (int k4 = 0; k4 < 16; k4++) {
        wc4[k4].x = W[(4 * k4 + 0) * 64 + lane];
        wc4[k4].y = W[(4 * k4 + 1) * 64 + lane];
        wc4[k4].z = W[(4 * k4 + 2) * 64 + lane];
        wc4[k4].w = W[(4 * k4 + 3) * 64 + lane];
    }
    float bj = bb[lane];
    float s1 = 0.f, s2 = 0.f;
    for (int r = 0; r < 16; r++) {
        int i = rowbase + r;
        if (i >= NN) break;
        float acc = bj;
        const float4* zr = (const float4*)&zw[r * 64];
        #pragma unroll
        for (int k4 = 0; k4 < 16; k4++) {
            float4 zv = zr[k4];
            acc = fmaf(zv.x, wc4[k4].x, acc);
            acc = fmaf(zv.y, wc4[k4].y, acc);
            acc = fmaf(zv.z, wc4[k4].z, acc);
            acc = fmaf(zv.w, wc4[k4].w, acc);
        }
        ubuf[i * 64 + lane] = acc;
        s1 += acc; s2 += acc * acc;
    }
    stats_flush(zbuf, t, lane, w, s1, s2, stats_out);
}

// ---------------- pass 2: BN1 apply + relu + GEMM2 + BN2 stats ----------------
// ZEROU: re-zero u for the next layer's agg. WB16: also store bf16 copy of output (gather table).
template <bool ZEROU, bool WB16>
__global__ __launch_bounds__(256, 4) void k_pass2(
    float* u,
    const float* __restrict__ ac1,
    const float* __restrict__ W, const float* __restrict__ bb,
    float* __restrict__ wout, ushort* __restrict__ hb16,
    float* __restrict__ stats_out)
{
    __shared__ float zbuf[64 * 64];
    int t = threadIdx.x, lane = t & 63, w = t >> 6;
    int rowbase = blockIdx.x * 64 + w * 16;
    float a = ac1[lane];
    float c = ac1[64 + lane];
    float* zw = &zbuf[w * 16 * 64];

    for (int r = 0; r < 16; r++) {
        int i = rowbase + r;
        float zf = 0.f;
        if (i < NN) {
            zf = fmaxf(fmaf(a, u[i * 64 + lane], c), 0.f);
            if (ZEROU) u[i * 64 + lane] = 0.f;
        }
        zw[r * 64 + lane] = zf;
    }

    float4 wc4[16];
    #pragma unroll
    for (int k4 = 0; k4 < 16; k4++) {
        wc4[k4].x = W[(4 * k4 + 0) * 64 + lane];
        wc4[k4].y = W[(4 * k4 + 1) * 64 + lane];
        wc4[k4].z = W[(4 * k4 + 2) * 64 + lane];
        wc4[k4].w = W[(4 * k4 + 3) * 64 + lane];
    }
    float bj = bb[lane];
    float s1 = 0.f, s2 = 0.f;
    for (int r = 0; r < 16; r++) {
        int i = rowbase + r;
        if (i >= NN) break;
        float acc = bj;
        const float4* zr = (const float4*)&zw[r * 64];
        #pragma unroll
        for (int k4 = 0; k4 < 16; k4++) {
            float4 zv = zr[k4];
            acc = fmaf(zv.x, wc4[k4].x, acc);
            acc = fmaf(zv.y, wc4[k4].y, acc);
            acc = fmaf(zv.z, wc4[k4].z, acc);
            acc = fmaf(zv.w, wc4[k4].w, acc);
        }
        wout[i * 64 + lane] = acc;
        if (WB16) hb16[i * 64 + lane] = f2b(acc);
        s1 += acc; s2 += acc * acc;
    }
    stats_flush(zbuf, t, lane, w, s1, s2, stats_out);
}

// ---------------- final: BN2 apply ×3 + concat-GEMM (K=192) + bias + relu + gate ----------------
// Round-9 structure (proven 136 µs): per-layer LDS staging, NO register prefetch pipeline
// (rounds 10/11: pf[16] live-range blowup -> scratch spill -> 9 GB HBM traffic).
__global__ __launch_bounds__(256, 4) void k_final(
    const float* __restrict__ w0, const float* __restrict__ w1, const float* __restrict__ w2,
    const float* __restrict__ acA, const float* __restrict__ acB, const float* __restrict__ acC,
    const float* __restrict__ lin1W, const float* __restrict__ lin1b,
    const float* __restrict__ gateW, const float* __restrict__ gateB,
    float* __restrict__ hh, float* __restrict__ gate)
{
    __shared__ float zbuf[64 * 64];
    int t = threadIdx.x, lane = t & 63, w = t >> 6;
    int rowbase = blockIdx.x * 64 + w * 16;
    float* zw = &zbuf[w * 16 * 64];

    float acc[16];
    #pragma unroll
    for (int r = 0; r < 16; r++) acc[r] = 0.f;

    for (int l = 0; l < 3; l++) {
        const float* wl = (l == 0) ? w0 : ((l == 1) ? w1 : w2);
        const float* ac = (l == 0) ? acA : ((l == 1) ? acB : acC);
        float a = ac[lane];
        float c = ac[64 + lane];

        for (int r = 0; r < 16; r++) {
            int i = rowbase + r;
            float zf = 0.f;
            if (i < NN) zf = fmaxf(fmaf(a, wl[i * 64 + lane], c), 0.f);
            zw[r * 64 + lane] = zf;
        }

        float4 wc4[16];
        #pragma unroll
        for (int k4 = 0; k4 < 16; k4++) {
            wc4[k4].x = lin1W[(l * 64 + 4 * k4 + 0) * 64 + lane];
            wc4[k4].y = lin1W[(l * 64 + 4 * k4 + 1) * 64 + lane];
            wc4[k4].z = lin1W[(l * 64 + 4 * k4 + 2) * 64 + lane];
            wc4[k4].w = lin1W[(l * 64 + 4 * k4 + 3) * 64 + lane];
        }

        #pragma unroll
        for (int r = 0; r < 16; r++) {
            const float4* zr = (const float4*)&zw[r * 64];
            float a2 = acc[r];
            #pragma unroll
            for (int k4 = 0; k4 < 16; k4++) {
                float4 zv = zr[k4];
                a2 = fmaf(zv.x, wc4[k4].x, a2);
                a2 = fmaf(zv.y, wc4[k4].y, a2);
                a2 = fmaf(zv.z, wc4[k4].z, a2);
                a2 = fmaf(zv.w, wc4[k4].w, a2);
            }
            acc[r] = a2;
        }
        __syncthreads();
    }

    float gw = gateW[lane];
    float gb = gateB[0];
    float lb = lin1b[lane];
    #pragma unroll
    for (int r = 0; r < 16; r++) {
        int i = rowbase + r;
        if (i < NN) {
            float h = fmaxf(acc[r] + lb, 0.f);
            hh[i * 64 + lane] = h;
            float gg = h * gw;
            for (int o = 32; o; o >>= 1) gg += __shfl_xor(gg, o);
            if (lane == 0) gate[i] = gg + gb;
        }
    }
}

// ---------------- graph boundaries + attentional pooling ----------------
__global__ void k_bounds(const int* __restrict__ batch_idx, int* __restrict__ gstart) {
    int g = blockIdx.x * 256 + threadIdx.x;
    if (g <= NGR) {
        int lo = 0, hi = NN;
        while (lo < hi) { int mid = (lo + hi) >> 1; if (batch_idx[mid] < g) lo = mid + 1; else hi = mid; }
        gstart[g] = lo;
    }
}

__global__ __launch_bounds__(256) void k_pool(const float* __restrict__ hh, const float* __restrict__ gate,
                                              const int* __restrict__ gstart, float* __restrict__ pooled) {
    __shared__ float red[4];
    __shared__ float pbuf[256];
    __shared__ float m_sh, d_sh;
    int g = blockIdx.x;
    int s = gstart[g], e = gstart[g + 1];
    int t = threadIdx.x, lane = t & 63, w = t >> 6;

    float m = -INFINITY;
    for (int i = s + t; i < e; i += 256) m = fmaxf(m, gate[i]);
    for (int o = 32; o; o >>= 1) m = fmaxf(m, __shfl_xor(m, o));
    if (lane == 0) red[w] = m;
    __syncthreads();
    if (t == 0) m_sh = fmaxf(fmaxf(red[0], red[1]), fmaxf(red[2], red[3]));
    __syncthreads();
    m = m_sh;

    float sum = 0.f;
    for (int i = s + t; i < e; i += 256) sum += expf(gate[i] - m);
    for (int o = 32; o; o >>= 1) sum += __shfl_xor(sum, o);
    if (lane == 0) red[w] = sum;
    __syncthreads();
    if (t == 0) d_sh = red[0] + red[1] + red[2] + red[3];
    __syncthreads();
    float denom = d_sh;

    float acc = 0.f;
    for (int i = s + w; i < e; i += 4) acc += expf(gate[i] - m) * hh[i * 64 + lane];
    pbuf[w * 64 + lane] = acc;
    __syncthreads();
    if (t < 64) {
        float tot = pbuf[t] + pbuf[64 + t] + pbuf[128 + t] + pbuf[192 + t];
        pooled[g * 64 + t] = (e > s) ? tot / denom : 0.f;
    }
}

// ---------------- launcher ----------------
extern "C" void kernel_launch(void* const* d_in, const int* in_sizes, int n_in,
                              void* d_out, int out_size, void* d_ws, size_t ws_size,
                              hipStream_t stream) {
    (void)in_sizes; (void)n_in; (void)out_size; (void)ws_size;
    const float* x     = (const float*)d_in[0];
    const int*   ei    = (const int*)d_in[1];
    const int*   src   = ei;
    const int*   dst   = ei + NE;
    const int*   bidx  = (const int*)d_in[2];
    const float* epsp  = (const float*)d_in[3];
    const float* W1    = (const float*)d_in[4];
    const float* b1    = (const float*)d_in[5];
    const float* g1    = (const float*)d_in[6];
    const float* be1   = (const float*)d_in[7];
    const float* W2    = (const float*)d_in[8];
    const float* b2    = (const float*)d_in[9];
    const float* g2    = (const float*)d_in[10];
    const float* be2   = (const float*)d_in[11];
    const float* lin1W = (const float*)d_in[12];
    const float* lin1b = (const float*)d_in[13];
    const float* gateW = (const float*)d_in[14];
    const float* gateB = (const float*)d_in[15];

    int* deg       = (int*)d_ws;
    int* cursor    = deg + NN;
    float* stats   = (float*)(cursor + NN);      // 6 instances * 8192 floats
    float* acbuf   = stats + 6 * INSTF;          // 6 * 128 floats compact BN coeffs
    int* row_start = (int*)(acbuf + 6 * 128);    // NN+1
    int* csr_src   = row_start + NN + 1;         // NE
    int* bsum      = csr_src + NE;               // 128
    // align the big fp32 tables to 256 B so ushort4/float4 access is legal
    size_t ofs = (size_t)((bsum + 128) - (int*)d_ws);      // in 4-byte units
    ofs = (ofs + 63) & ~(size_t)63;
    float* u       = (float*)d_ws + ofs;         // NN*64  (agg + gemm1 out, aliased)
    float* w0      = u   + (size_t)NN * 64;
    float* w1v     = w0  + (size_t)NN * 64;
    float* w2v     = w1v + (size_t)NN * 64;
    float* gate    = w2v + (size_t)NN * 64;      // NN
    int* gstart    = (int*)(gate + NN);          // NGR+1

    // bf16 gather table ALIASES w2v: last hb read (agg layer2) precedes pass2_2's w2v write.
    ushort* hb = (ushort*)w2v;

    float* hh     = (float*)d_out;
    float* pooled = hh + (size_t)NN * 64;

    // zero deg, cursor, and all stats slots (ac buffers fully overwritten by k_bnred)
    hipMemsetAsync(d_ws, 0, (size_t)(2 * NN + 6 * INSTF) * 4, stream);

    k_count<<<(NE + 255) / 256, 256, 0, stream>>>(dst, deg);
    int nb = (NN + 1023) / 1024;
    k_blocksum<<<nb, 256, 0, stream>>>(deg, bsum);
    k_scanbsum<<<1, 64, 0, stream>>>(bsum, nb, row_start);
    k_scanblocks<<<nb, 256, 0, stream>>>(deg, bsum, row_start);
    k_fill<<<(NE + 255) / 256, 256, 0, stream>>>(src, dst, row_start, cursor, csr_src);

    int nagg  = NE / CHUNK;          // 6250 waves
    int nblk  = (NN + 63) / 64;      // 1563 blocks for GEMM kernels
    int ncvt  = (NN * 64) / (256 * 4);   // 6250
    size_t hbytes = (size_t)NN * 64 * 4;

    float* sl0bn1 = stats + 0 * INSTF;  float* ac0bn1 = acbuf + 0 * 128;
    float* sl0bn2 = stats + 1 * INSTF;  float* ac0bn2 = acbuf + 1 * 128;
    float* sl1bn1 = stats + 2 * INSTF;  float* ac1bn1 = acbuf + 2 * 128;
    float* sl1bn2 = stats + 3 * INSTF;  float* ac1bn2 = acbuf + 3 * 128;
    float* sl2bn1 = stats + 4 * INSTF;  float* ac2bn1 = acbuf + 4 * 128;
    float* sl2bn2 = stats + 5 * INSTF;  float* ac2bn2 = acbuf + 5 * 128;

    // layer 0
    hipMemsetAsync(u, 0, hbytes, stream);
    k_cvt<<<ncvt, 256, 0, stream>>>(x, hb);
    k_agg<false><<<nagg, 64, 0, stream>>>(hb, nullptr, row_start, csr_src, u);
    k_mlp1<false><<<nblk, 256, 0, stream>>>(x, u, nullptr, epsp, 0, W1, b1, sl0bn1);
    k_bnred<<<1, 64, 0, stream>>>(sl0bn1, g1, be1, ac0bn1);
    k_pass2<true, true><<<nblk, 256, 0, stream>>>(u, ac0bn1, W2, b2, w0, hb, sl0bn2);
    k_bnred<<<1, 64, 0, stream>>>(sl0bn2, g2, be2, ac0bn2);
    // layer 1
    k_agg<true><<<nagg, 64, 0, stream>>>(hb, ac0bn2, row_start, csr_src, u);
    k_mlp1<true><<<nblk, 256, 0, stream>>>(w0, u, ac0bn2, epsp, 1, W1 + 4096, b1 + 64, sl1bn1);
    k_bnred<<<1, 64, 0, stream>>>(sl1bn1, g1 + 64, be1 + 64, ac1bn1);
    k_pass2<true, true><<<nblk, 256, 0, stream>>>(u, ac1bn1, W2 + 4096, b2 + 64, w1v, hb, sl1bn2);
    k_bnred<<<1, 64, 0, stream>>>(sl1bn2, g2 + 64, be2 + 64, ac1bn2);
    // layer 2
    k_agg<true><<<nagg, 64, 0, stream>>>(hb, ac1bn2, row_start, csr_src, u);
    k_mlp1<true><<<nblk, 256, 0, stream>>>(w1v, u, ac1bn2, epsp, 2, W1 + 8192, b1 + 128, sl2bn1);
    k_bnred<<<1, 64, 0, stream>>>(sl2bn1, g1 + 128, be1 + 128, ac2bn1);
    k_pass2<false, false><<<nblk, 256, 0, stream>>>(u, ac2bn1, W2 + 8192, b2 + 128, w2v, nullptr, sl2bn2);
    k_bnred<<<1, 64, 0, stream>>>(sl2bn2, g2 + 128, be2 + 128, ac2bn2);

    k_final<<<nblk, 256, 0, stream>>>(w0, w1v, w2v, ac0bn2, ac1bn2, ac2bn2,
                                      lin1W, lin1b, gateW, gateB, hh, gate);
    k_bounds<<<(NGR + 256) / 256, 256, 0, stream>>>(bidx, gstart);
    k_pool<<<NGR, 256, 0, stream>>>(hh, gate, gstart, pooled);
}